// Round 4
// baseline (217.058 us; speedup 1.0000x reference)
//
#include <hip/hip_runtime.h>
#include <hip/hip_bf16.h>

// Attention B=4,N=2048,D=384,H=8,DH=48 — Round 17b (R17 + cvt_pkrtz bitcast fix):
//  - attn: R14/R15 LDS-staged structure. Changes vs R14:
//      * raw v_exp_f32 (__builtin_amdgcn_exp2f) instead of libm exp2f
//      * packed v_cvt_pkrtz_f16_f32 (16 converts/tile instead of 32)
//      * ones-row l (no VALU), double-buffer LDS + ONE barrier/tile, setprio
//      * V pre-permuted in qkv epilogue -> contiguous b128 V staging
//      * LDS strides 58/74 (odd bank stride -> no 4-way ds_read conflicts)
//  - qkv: R16 version (kappa perm in V epilogue). prep/proj unchanged.

typedef _Float16 f16x8 __attribute__((ext_vector_type(8)));
typedef _Float16 f16x4 __attribute__((ext_vector_type(4)));
typedef _Float16 f16x2 __attribute__((ext_vector_type(2)));
typedef float    f32x4 __attribute__((ext_vector_type(4)));
typedef float    f32x16 __attribute__((ext_vector_type(16)));

// scale * log2(e) = 48^-0.5 * 1.4426950408889634
#define QSCL 0.20822035963448658f

// packed f32x2 -> f16x2 convert (cvt_pkrtz returns __fp16x2; bitcast to f16x2)
static __device__ __forceinline__ f16x2 cvt_pk_f16(float a, float b) {
    return __builtin_bit_cast(f16x2, __builtin_amdgcn_cvt_pkrtz(a, b));
}

// ---------------------------------------------------------------------------
// prep: blocks 0..143 transpose weights (LDS-tiled); 144..399 convert x->f16
// ---------------------------------------------------------------------------
__global__ __launch_bounds__(256) void prep(const float4* __restrict__ x,
                                            const float* __restrict__ wq,
                                            const float* __restrict__ wp,
                                            f16x4* __restrict__ xh4,
                                            _Float16* __restrict__ wqt,
                                            _Float16* __restrict__ wpt)
{
    __shared__ _Float16 t[64][65];
    const int blk = blockIdx.x, tid = threadIdx.x;
    if (blk < 144) {
        const float* src; _Float16* dst; int Nn, k0, n0;
        if (blk < 108) {            // Wqkv: 6 k-tiles x 18 n-tiles
            src = wq; dst = wqt; Nn = 1152;
            k0 = (blk % 6) * 64; n0 = (blk / 6) * 64;
        } else {                    // Wproj: 6 x 6
            const int b2 = blk - 108;
            src = wp; dst = wpt; Nn = 384;
            k0 = (b2 % 6) * 64; n0 = (b2 / 6) * 64;
        }
        #pragma unroll
        for (int i = 0; i < 16; i++) {
            const int id = tid + i * 256;
            const int k = id >> 6, n = id & 63;      // coalesced over n
            t[k][n] = (_Float16)src[(size_t)(k0 + k) * Nn + n0 + n];
        }
        __syncthreads();
        #pragma unroll
        for (int i = 0; i < 16; i++) {
            const int id = tid + i * 256;
            const int n = id >> 6, k = id & 63;      // coalesced over k
            dst[(size_t)(n0 + n) * 384 + k0 + k] = t[k][n];
        }
    } else {
        const int base = (blk - 144) * 3072;         // 256 blocks x 3072 = 786432
        #pragma unroll
        for (int r = 0; r < 12; r++) {
            const int j = base + r * 256 + tid;
            const float4 tt = x[j];
            f16x4 hh;
            hh[0] = (_Float16)tt.x; hh[1] = (_Float16)tt.y;
            hh[2] = (_Float16)tt.z; hh[3] = (_Float16)tt.w;
            xh4[j] = hh;
        }
    }
}

// ---------------------------------------------------------------------------
// QKV GEMM: A = xh[8192][384] f16, Bt = wqkvt[1152][384] f16.
// 128x128 tile, BK=32, padded LDS (stride 40), 16x16x32 MFMA, 4 waves,
// reg-prefetch. Epilogue via LDS transpose -> coalesced f16x8 stores.
// V epilogue stores the kappa-permuted token order (bits 2<->3 of token%16)
// so attn's PV A-fragments are contiguous f16x8 loads.
// ---------------------------------------------------------------------------
union QkvSmem {
    struct { _Float16 As[128][40]; _Float16 Bs[128][40]; } g;  // 20480 B
    _Float16 Ts[128][136];   // V transpose   [col][n]   34816 B
    _Float16 Ts2[128][136];  // q/k transpose [row][col] 34816 B
};

__global__ __launch_bounds__(256) void qkv_f16(const _Float16* __restrict__ A,
                                               const _Float16* __restrict__ Bt,
                                               _Float16* __restrict__ qh,
                                               _Float16* __restrict__ kh,
                                               _Float16* __restrict__ vt)
{
    __shared__ QkvSmem sm;
    const int tid = threadIdx.x;
    const int w = tid >> 6, lane = tid & 63, cl = lane & 15, quad = lane >> 4;
    const int bm = blockIdx.x, bn = blockIdx.y;

    f32x4 acc[2][8];
    const f32x4 z4 = {0.f, 0.f, 0.f, 0.f};
    #pragma unroll
    for (int mi = 0; mi < 2; mi++)
        #pragma unroll
        for (int t = 0; t < 8; t++) acc[mi][t] = z4;

    const int ar = tid >> 2, ac = (tid & 3) * 8;     // 512 chunks: 2/thread
    const _Float16* Ag = A  + (size_t)(bm * 128 + ar) * 384 + ac;
    const _Float16* Bg = Bt + (size_t)(bn * 128 + ar) * 384 + ac;

    f16x8 pa[2], pb[2];
    #pragma unroll
    for (int j = 0; j < 2; j++) {
        pa[j] = *(const f16x8*)(Ag + (size_t)(64 * j) * 384);
        pb[j] = *(const f16x8*)(Bg + (size_t)(64 * j) * 384);
    }

    for (int k0 = 0; k0 < 384; k0 += 32) {
        __syncthreads();
        #pragma unroll
        for (int j = 0; j < 2; j++) {
            *(f16x8*)&sm.g.As[ar + 64 * j][ac] = pa[j];
            *(f16x8*)&sm.g.Bs[ar + 64 * j][ac] = pb[j];
        }
        __syncthreads();
        if (k0 + 32 < 384) {
            #pragma unroll
            for (int j = 0; j < 2; j++) {
                pa[j] = *(const f16x8*)(Ag + (size_t)(64 * j) * 384 + k0 + 32);
                pb[j] = *(const f16x8*)(Bg + (size_t)(64 * j) * 384 + k0 + 32);
            }
        }
        f16x8 bf[8];
        #pragma unroll
        for (int t = 0; t < 8; t++)
            bf[t] = *(const f16x8*)&sm.g.Bs[t * 16 + cl][quad * 8];
        #pragma unroll
        for (int mi = 0; mi < 2; mi++) {
            const f16x8 af = *(const f16x8*)&sm.g.As[w * 32 + mi * 16 + cl][quad * 8];
            #pragma unroll
            for (int t = 0; t < 8; t++)
                acc[mi][t] = __builtin_amdgcn_mfma_f32_16x16x32_f16(af, bf[t], acc[mi][t], 0, 0, 0);
        }
    }

    const int s = (bn * 128) / 384;    // uniform per block (384 % 128 == 0)
    const int b  = (bm * 128) >> 11;
    const int n0 = (bm * 128) & 2047;
    if (s == 2) {
        // ---- V: LDS transpose [col][token'] with kappa perm on token%16 ----
        __syncthreads();
        const int qp = ((quad & 1) << 1) | (quad >> 1);   // swap bits of quad
        #pragma unroll
        for (int t = 0; t < 8; t++)
            #pragma unroll
            for (int mi = 0; mi < 2; mi++)
                #pragma unroll
                for (int r = 0; r < 4; r++)
                    sm.Ts[t * 16 + cl][w * 32 + mi * 16 + qp * 4 + r] =
                        (_Float16)acc[mi][t][r];
        __syncthreads();
        const int colbase = bn * 128 - 768;      // 0,128,256
        #pragma unroll
        for (int i = 0; i < 8; i++) {
            const int c = i * 256 + tid;         // 0..2047 chunks of 8
            const int col = c >> 4, nc = c & 15;
            const int gcol = colbase + col;
            const int head = gcol / 48, d = gcol - head * 48;
            const int bh = b * 8 + head;
            *(f16x8*)&vt[(size_t)(bh * 48 + d) * 2048 + n0 + nc * 8] =
                *(const f16x8*)&sm.Ts[col][nc * 8];
        }
    } else {
        // ---- q/k: LDS transpose [row][col] -> coalesced f16x8 stores ----
        __syncthreads();
        const float scl = (s == 0) ? QSCL : 1.0f;
        #pragma unroll
        for (int t = 0; t < 8; t++)
            #pragma unroll
            for (int mi = 0; mi < 2; mi++)
                #pragma unroll
                for (int r = 0; r < 4; r++)
                    sm.Ts2[w * 32 + mi * 16 + quad * 4 + r][t * 16 + cl] =
                        (_Float16)(acc[mi][t][r] * scl);
        __syncthreads();
        _Float16* dst = (s == 0) ? qh : kh;
        const int colbase = bn * 128 - s * 384;  // 0,128,256
        #pragma unroll
        for (int i = 0; i < 8; i++) {
            const int c = i * 256 + tid;         // 0..2047 chunks of 8
            const int row = c >> 4, ch = c & 15;
            const int gcol = colbase + ch * 8;   // multiple of 8; 48=6x8 -> no straddle
            const int head = gcol / 48, d = gcol - head * 48;
            const int bh = b * 8 + head;
            *(f16x8*)&dst[(size_t)(bh * 2048 + n0 + row) * 48 + d] =
                *(const f16x8*)&sm.Ts2[row][ch * 8];
        }
    }
}

// ---------------------------------------------------------------------------
// Flash attention (R17): LDS-staged, double-buffered, ONE barrier per tile.
// 32x32x16 f16 MFMA, no-max softmax with raw v_exp_f32 + v_cvt_pkrtz,
// register-P (global V already kappa-permuted), l via ones-row 48.
// ---------------------------------------------------------------------------
#define KS_S 58   // Ks stride: 116 B -> bank stride 29 (odd, conflict-free)
#define VS_S 74   // Vts stride: 148 B -> bank stride 37 (odd, conflict-free)

union AttnSmem {
    struct {
        _Float16 Ks[2][64][KS_S];    // [buf][key][dh]       14848 B
        _Float16 Vts[2][64][VS_S];   // [buf][dh'][slot]     18944 B; row 48 ones
    } a;                             // 33792 B
    _Float16 Ot[128][58];            // epilogue transpose   14848 B
};

__global__ __launch_bounds__(256) void attn_f16(const _Float16* __restrict__ qh,
                                                const _Float16* __restrict__ kh,
                                                const _Float16* __restrict__ vt,
                                                _Float16* __restrict__ ab)
{
    __shared__ AttnSmem sm;
    const int tid = threadIdx.x;
    const int w = tid >> 6, lane = tid & 63, ln = lane & 31, h = lane >> 5;
    const int bh = blockIdx.x, qt = blockIdx.y;

    // one-time: Vts rows 48..63 for BOTH buffers (48 = ones for l, rest zero)
    for (int i = tid; i < 2 * 16 * VS_S; i += 256) {
        const int bi = i / (16 * VS_S), j = i - bi * (16 * VS_S);
        const int r = 48 + j / VS_S, c = j - (j / VS_S) * VS_S;
        sm.a.Vts[bi][r][c] = (r == 48) ? (_Float16)1.0f : (_Float16)0.0f;
    }

    // Q B-frags (3, dh = 16i + 8h + 0..7), query = qt*128 + w*32 + ln
    f16x8 qf[3];
    {
        const _Float16* qp = qh + (size_t)(bh * 2048 + qt * 128 + w * 32 + ln) * 48 + 8 * h;
        qf[0] = *(const f16x8*)qp;
        qf[1] = *(const f16x8*)(qp + 16);
        qf[2] = *(const f16x8*)(qp + 32);
    }

    f32x16 o0, o1;
    #pragma unroll
    for (int r = 0; r < 16; r++) { o0[r] = 0.f; o1[r] = 0.f; }

    const _Float16* kbase = kh + (size_t)bh * 2048 * 48;
    const _Float16* vbase = vt + (size_t)bh * 48 * 2048;

    // staging decomposition: K = 64 rows x 6 chunks = 384; V = 48 rows x 8 = 384
    const int kr0 = tid / 6,        kc0 = (tid % 6) * 8;
    const int kid1 = tid + 256;
    const int kr1 = kid1 / 6,       kc1 = (kid1 % 6) * 8;
    const int vr0 = tid >> 3,       vc0 = (tid & 7) * 8;   // rows 0..31
    const int vr1 = vr0 + 32;                              // rows 32..47 (tid<128)
    const _Float16* ks0 = kbase + (size_t)kr0 * 48 + kc0;
    const _Float16* ks1 = kbase + (size_t)kr1 * 48 + kc1;
    const _Float16* vs0 = vbase + (size_t)vr0 * 2048 + vc0;
    const _Float16* vs1 = vbase + (size_t)vr1 * 2048 + vc0;

    f16x8 rk0 = *(const f16x8*)ks0;
    f16x8 rv0 = *(const f16x8*)vs0;
    f16x8 rk1, rv1;
    if (tid < 128) { rk1 = *(const f16x8*)ks1; rv1 = *(const f16x8*)vs1; }

    for (int t = 0; t < 32; ++t) {
        _Float16 (*Ksb)[KS_S] = sm.a.Ks[t & 1];
        _Float16 (*Vtb)[VS_S] = sm.a.Vts[t & 1];

        // ---- stage regs -> LDS[buf]: contiguous b128 writes ----
        *(f16x8*)&Ksb[kr0][kc0] = rk0;
        *(f16x8*)&Vtb[vr0][vc0] = rv0;
        if (tid < 128) {
            *(f16x8*)&Ksb[kr1][kc1] = rk1;
            *(f16x8*)&Vtb[vr1][vc0] = rv1;
        }
        __syncthreads();   // single barrier/tile: dbuf covers write-after-read

        // ---- prefetch next tile into regs (in flight across compute) ----
        if (t < 31) {
            const int off = (t + 1) * 64;
            rk0 = *(const f16x8*)(ks0 + (size_t)off * 48);
            rv0 = *(const f16x8*)(vs0 + off);
            if (tid < 128) {
                rk1 = *(const f16x8*)(ks1 + (size_t)off * 48);
                rv1 = *(const f16x8*)(vs1 + off);
            }
        }

        // ---- S^T = K.Q^T : C[key][query] ----
        f32x16 s0, s1;
        #pragma unroll
        for (int r = 0; r < 16; r++) { s0[r] = 0.f; s1[r] = 0.f; }
        __builtin_amdgcn_s_setprio(1);
        #pragma unroll
        for (int i = 0; i < 3; i++) {
            const f16x8 ka0 = *(const f16x8*)&Ksb[ln][16 * i + 8 * h];
            s0 = __builtin_amdgcn_mfma_f32_32x32x16_f16(ka0, qf[i], s0, 0, 0, 0);
            const f16x8 ka1 = *(const f16x8*)&Ksb[32 + ln][16 * i + 8 * h];
            s1 = __builtin_amdgcn_mfma_f32_32x32x16_f16(ka1, qf[i], s1, 0, 0, 0);
        }
        __builtin_amdgcn_s_setprio(0);

        // ---- P = exp2(S^T): raw v_exp_f32 + packed cvt (v_cvt_pkrtz) ----
        f16x8 pbf[4];
        f16x2* pp = (f16x2*)pbf;   // pp[4c + m] = pbf[c] halves
        #pragma unroll
        for (int m = 0; m < 4; m++) {
            pp[m]      = cvt_pk_f16(
                __builtin_amdgcn_exp2f(s0[2 * m]),     __builtin_amdgcn_exp2f(s0[2 * m + 1]));
            pp[4 + m]  = cvt_pk_f16(
                __builtin_amdgcn_exp2f(s0[8 + 2 * m]), __builtin_amdgcn_exp2f(s0[9 + 2 * m]));
            pp[8 + m]  = cvt_pk_f16(
                __builtin_amdgcn_exp2f(s1[2 * m]),     __builtin_amdgcn_exp2f(s1[2 * m + 1]));
            pp[12 + m] = cvt_pk_f16(
                __builtin_amdgcn_exp2f(s1[8 + 2 * m]), __builtin_amdgcn_exp2f(s1[9 + 2 * m]));
        }

        // ---- O^T += V^T.P^T (ones row 48 accumulates l into o1[8]@h=0) ----
        __builtin_amdgcn_s_setprio(1);
        #pragma unroll
        for (int c = 0; c < 4; c++) {
            const f16x8 av0 = *(const f16x8*)&Vtb[ln][16 * c + 8 * h];
            o0 = __builtin_amdgcn_mfma_f32_32x32x16_f16(av0, pbf[c], o0, 0, 0, 0);
            const f16x8 av1 = *(const f16x8*)&Vtb[32 + ln][16 * c + 8 * h];
            o1 = __builtin_amdgcn_mfma_f32_32x32x16_f16(av1, pbf[c], o1, 0, 0, 0);
        }
        __builtin_amdgcn_s_setprio(0);
    }

    // ---- l(q) = O^T row 48 = o1 reg 8 on h=0 lanes (their query = ln) ----
    const float lr  = __shfl(o1[8], ln);
    const float inv = 1.f / lr;

    // ---- epilogue: O^T -> LDS transpose -> coalesced stores ----
    __syncthreads();
    #pragma unroll
    for (int r = 0; r < 16; r++)
        sm.Ot[w * 32 + ln][(r & 3) + 8 * (r >> 2) + 4 * h] = (_Float16)(o0[r] * inv);
    #pragma unroll
    for (int r = 0; r < 8; r++)
        sm.Ot[w * 32 + ln][32 + (r & 3) + 8 * (r >> 2) + 4 * h] = (_Float16)(o1[r] * inv);
    __syncthreads();
    const int b = bh >> 3, hd = bh & 7;
    #pragma unroll
    for (int i = 0; i < 3; i++) {
        const int c2 = i * 256 + tid;
        const int row = c2 / 6, ch = c2 % 6;
        const int q = qt * 128 + row;
        *(f16x8*)&ab[(size_t)(b * 2048 + q) * 384 + hd * 48 + ch * 8] =
            *(const f16x8*)&sm.Ot[row][ch * 8];
    }
}

// ---------------------------------------------------------------------------
// Proj GEMM: A = ab[8192][384] f16, Bt = wprojt[384][384] f16, +bias -> fp32
// 64x64 tile, BK=64, padded LDS, reg-prefetch.
// ---------------------------------------------------------------------------
__global__ __launch_bounds__(256) void proj_f16(const _Float16* __restrict__ A,
                                                const _Float16* __restrict__ Bt,
                                                const float* __restrict__ bias,
                                                float* __restrict__ out)
{
    __shared__ _Float16 As[64][72];
    __shared__ _Float16 Bs[64][72];
    const int tid = threadIdx.x;
    const int w = tid >> 6, lane = tid & 63, cl = lane & 15, quad = lane >> 4;
    const int bm = blockIdx.x, bn = blockIdx.y;

    f32x4 acc[4];
    const f32x4 z4 = {0.f, 0.f, 0.f, 0.f};
    #pragma unroll
    for (int t = 0; t < 4; t++) acc[t] = z4;

    const int ar = tid >> 3, ac = (tid & 7) * 8;
    const _Float16* Ag = A  + (size_t)(bm * 64 + ar) * 384 + ac;
    const _Float16* Bg = Bt + (size_t)(bn * 64 + ar) * 384 + ac;

    f16x8 pa[2], pb[2];
    #pragma unroll
    for (int j = 0; j < 2; j++) {
        pa[j] = *(const f16x8*)(Ag + (size_t)(32 * j) * 384);
        pb[j] = *(const f16x8*)(Bg + (size_t)(32 * j) * 384);
    }

    for (int k0 = 0; k0 < 384; k0 += 64) {
        __syncthreads();
        #pragma unroll
        for (int j = 0; j < 2; j++) {
            *(f16x8*)&As[ar + 32 * j][ac] = pa[j];
            *(f16x8*)&Bs[ar + 32 * j][ac] = pb[j];
        }
        __syncthreads();
        if (k0 + 64 < 384) {
            #pragma unroll
            for (int j = 0; j < 2; j++) {
                pa[j] = *(const f16x8*)(Ag + (size_t)(32 * j) * 384 + k0 + 64);
                pb[j] = *(const f16x8*)(Bg + (size_t)(32 * j) * 384 + k0 + 64);
            }
        }
        #pragma unroll
        for (int kh2 = 0; kh2 < 2; kh2++) {
            const f16x8 af = *(const f16x8*)&As[w * 16 + cl][kh2 * 32 + quad * 8];
            #pragma unroll
            for (int t = 0; t < 4; t++) {
                const f16x8 bf = *(const f16x8*)&Bs[t * 16 + cl][kh2 * 32 + quad * 8];
                acc[t] = __builtin_amdgcn_mfma_f32_16x16x32_f16(af, bf, acc[t], 0, 0, 0);
            }
        }
    }

    #pragma unroll
    for (int t = 0; t < 4; t++) {
        const int col = bn * 64 + t * 16 + cl;
        const float bv = bias[col];
        #pragma unroll
        for (int r = 0; r < 4; r++) {
            const int row = bm * 64 + w * 16 + quad * 4 + r;
            out[(size_t)row * 384 + col] = acc[t][r] + bv;
        }
    }
}

// ---------------------------------------------------------------------------
extern "C" void kernel_launch(void* const* d_in, const int* in_sizes, int n_in,
                              void* d_out, int out_size, void* d_ws, size_t ws_size,
                              hipStream_t stream) {
    const float* x     = (const float*)d_in[0];  // [4,2048,384]
    const float* Wqkv  = (const float*)d_in[1];  // [384,1152]
    const float* Wproj = (const float*)d_in[2];  // [384,384]
    const float* bproj = (const float*)d_in[3];  // [384]
    float* out = (float*)d_out;

    char* ws = (char*)d_ws;
    _Float16* xh     = (_Float16*)(ws + 0);          // 8192*384*2  = 6,291,456
    _Float16* wqkvt  = (_Float16*)(ws + 6291456);    // 1152*384*2  =   884,736
    _Float16* wprojt = (_Float16*)(ws + 7176192);    // 384*384*2   =   294,912
    _Float16* qh     = (_Float16*)(ws + 7471104);    // 32*2048*48*2 = 6,291,456
    _Float16* kh     = (_Float16*)(ws + 13762560);   // 6,291,456
    _Float16* vt     = (_Float16*)(ws + 20054016);   // 6,291,456
    _Float16* ab     = (_Float16*)(ws + 26345472);   // 6,291,456
    // total 32,636,928 B

    prep<<<400, 256, 0, stream>>>((const float4*)x, Wqkv, Wproj,
                                  (f16x4*)xh, wqkvt, wprojt);
    qkv_f16<<<dim3(64, 9), 256, 0, stream>>>(xh, wqkvt, qh, kh, vt);
    attn_f16<<<dim3(32, 16), 256, 0, stream>>>(qh, kh, vt, ab);
    proj_f16<<<dim3(128, 6), 256, 0, stream>>>(ab, wprojt, bproj, out);
}

// Round 5
// 133.278 us; speedup vs baseline: 1.6286x; 1.6286x over previous
//
#include <hip/hip_runtime.h>
#include <hip/hip_bf16.h>

// Attention B=4,N=2048,D=384,H=8,DH=48 — Round 18 (R17b with ALIGNED strides):
//  - attn: R14 LDS-staged structure + slim softmax. vs R17b: LDS strides back
//    to 56/72 (112/144 B -> every hot ds_read/ds_write_b128 is 16B-aligned;
//    R17b's odd strides 58/74 made the compiler split every b128 -> 2x slower).
//    Kept: raw v_exp_f32, packed v_cvt_pkrtz, ones-row l, single-barrier
//    double-buffer, setprio, pre-permuted V -> contiguous b128 V staging.
//  - qkv: R16 version (kappa perm in V epilogue). prep/proj unchanged.

typedef _Float16 f16x8 __attribute__((ext_vector_type(8)));
typedef _Float16 f16x4 __attribute__((ext_vector_type(4)));
typedef _Float16 f16x2 __attribute__((ext_vector_type(2)));
typedef float    f32x4 __attribute__((ext_vector_type(4)));
typedef float    f32x16 __attribute__((ext_vector_type(16)));

// scale * log2(e) = 48^-0.5 * 1.4426950408889634
#define QSCL 0.20822035963448658f

// packed f32x2 -> f16x2 convert (cvt_pkrtz returns __fp16x2; bitcast to f16x2)
static __device__ __forceinline__ f16x2 cvt_pk_f16(float a, float b) {
    return __builtin_bit_cast(f16x2, __builtin_amdgcn_cvt_pkrtz(a, b));
}

// ---------------------------------------------------------------------------
// prep: blocks 0..143 transpose weights (LDS-tiled); 144..399 convert x->f16
// ---------------------------------------------------------------------------
__global__ __launch_bounds__(256) void prep(const float4* __restrict__ x,
                                            const float* __restrict__ wq,
                                            const float* __restrict__ wp,
                                            f16x4* __restrict__ xh4,
                                            _Float16* __restrict__ wqt,
                                            _Float16* __restrict__ wpt)
{
    __shared__ _Float16 t[64][65];
    const int blk = blockIdx.x, tid = threadIdx.x;
    if (blk < 144) {
        const float* src; _Float16* dst; int Nn, k0, n0;
        if (blk < 108) {            // Wqkv: 6 k-tiles x 18 n-tiles
            src = wq; dst = wqt; Nn = 1152;
            k0 = (blk % 6) * 64; n0 = (blk / 6) * 64;
        } else {                    // Wproj: 6 x 6
            const int b2 = blk - 108;
            src = wp; dst = wpt; Nn = 384;
            k0 = (b2 % 6) * 64; n0 = (b2 / 6) * 64;
        }
        #pragma unroll
        for (int i = 0; i < 16; i++) {
            const int id = tid + i * 256;
            const int k = id >> 6, n = id & 63;      // coalesced over n
            t[k][n] = (_Float16)src[(size_t)(k0 + k) * Nn + n0 + n];
        }
        __syncthreads();
        #pragma unroll
        for (int i = 0; i < 16; i++) {
            const int id = tid + i * 256;
            const int n = id >> 6, k = id & 63;      // coalesced over k
            dst[(size_t)(n0 + n) * 384 + k0 + k] = t[k][n];
        }
    } else {
        const int base = (blk - 144) * 3072;         // 256 blocks x 3072 = 786432
        #pragma unroll
        for (int r = 0; r < 12; r++) {
            const int j = base + r * 256 + tid;
            const float4 tt = x[j];
            f16x4 hh;
            hh[0] = (_Float16)tt.x; hh[1] = (_Float16)tt.y;
            hh[2] = (_Float16)tt.z; hh[3] = (_Float16)tt.w;
            xh4[j] = hh;
        }
    }
}

// ---------------------------------------------------------------------------
// QKV GEMM: A = xh[8192][384] f16, Bt = wqkvt[1152][384] f16.
// 128x128 tile, BK=32, padded LDS (stride 40), 16x16x32 MFMA, 4 waves,
// reg-prefetch. Epilogue via LDS transpose -> coalesced f16x8 stores.
// V epilogue stores the kappa-permuted token order (bits 2<->3 of token%16)
// so attn's PV A-fragments are contiguous f16x8 loads.
// ---------------------------------------------------------------------------
union QkvSmem {
    struct { _Float16 As[128][40]; _Float16 Bs[128][40]; } g;  // 20480 B
    _Float16 Ts[128][136];   // V transpose   [col][n]   34816 B
    _Float16 Ts2[128][136];  // q/k transpose [row][col] 34816 B
};

__global__ __launch_bounds__(256) void qkv_f16(const _Float16* __restrict__ A,
                                               const _Float16* __restrict__ Bt,
                                               _Float16* __restrict__ qh,
                                               _Float16* __restrict__ kh,
                                               _Float16* __restrict__ vt)
{
    __shared__ QkvSmem sm;
    const int tid = threadIdx.x;
    const int w = tid >> 6, lane = tid & 63, cl = lane & 15, quad = lane >> 4;
    const int bm = blockIdx.x, bn = blockIdx.y;

    f32x4 acc[2][8];
    const f32x4 z4 = {0.f, 0.f, 0.f, 0.f};
    #pragma unroll
    for (int mi = 0; mi < 2; mi++)
        #pragma unroll
        for (int t = 0; t < 8; t++) acc[mi][t] = z4;

    const int ar = tid >> 2, ac = (tid & 3) * 8;     // 512 chunks: 2/thread
    const _Float16* Ag = A  + (size_t)(bm * 128 + ar) * 384 + ac;
    const _Float16* Bg = Bt + (size_t)(bn * 128 + ar) * 384 + ac;

    f16x8 pa[2], pb[2];
    #pragma unroll
    for (int j = 0; j < 2; j++) {
        pa[j] = *(const f16x8*)(Ag + (size_t)(64 * j) * 384);
        pb[j] = *(const f16x8*)(Bg + (size_t)(64 * j) * 384);
    }

    for (int k0 = 0; k0 < 384; k0 += 32) {
        __syncthreads();
        #pragma unroll
        for (int j = 0; j < 2; j++) {
            *(f16x8*)&sm.g.As[ar + 64 * j][ac] = pa[j];
            *(f16x8*)&sm.g.Bs[ar + 64 * j][ac] = pb[j];
        }
        __syncthreads();
        if (k0 + 32 < 384) {
            #pragma unroll
            for (int j = 0; j < 2; j++) {
                pa[j] = *(const f16x8*)(Ag + (size_t)(64 * j) * 384 + k0 + 32);
                pb[j] = *(const f16x8*)(Bg + (size_t)(64 * j) * 384 + k0 + 32);
            }
        }
        f16x8 bf[8];
        #pragma unroll
        for (int t = 0; t < 8; t++)
            bf[t] = *(const f16x8*)&sm.g.Bs[t * 16 + cl][quad * 8];
        #pragma unroll
        for (int mi = 0; mi < 2; mi++) {
            const f16x8 af = *(const f16x8*)&sm.g.As[w * 32 + mi * 16 + cl][quad * 8];
            #pragma unroll
            for (int t = 0; t < 8; t++)
                acc[mi][t] = __builtin_amdgcn_mfma_f32_16x16x32_f16(af, bf[t], acc[mi][t], 0, 0, 0);
        }
    }

    const int s = (bn * 128) / 384;    // uniform per block (384 % 128 == 0)
    const int b  = (bm * 128) >> 11;
    const int n0 = (bm * 128) & 2047;
    if (s == 2) {
        // ---- V: LDS transpose [col][token'] with kappa perm on token%16 ----
        __syncthreads();
        const int qp = ((quad & 1) << 1) | (quad >> 1);   // swap bits of quad
        #pragma unroll
        for (int t = 0; t < 8; t++)
            #pragma unroll
            for (int mi = 0; mi < 2; mi++)
                #pragma unroll
                for (int r = 0; r < 4; r++)
                    sm.Ts[t * 16 + cl][w * 32 + mi * 16 + qp * 4 + r] =
                        (_Float16)acc[mi][t][r];
        __syncthreads();
        const int colbase = bn * 128 - 768;      // 0,128,256
        #pragma unroll
        for (int i = 0; i < 8; i++) {
            const int c = i * 256 + tid;         // 0..2047 chunks of 8
            const int col = c >> 4, nc = c & 15;
            const int gcol = colbase + col;
            const int head = gcol / 48, d = gcol - head * 48;
            const int bh = b * 8 + head;
            *(f16x8*)&vt[(size_t)(bh * 48 + d) * 2048 + n0 + nc * 8] =
                *(const f16x8*)&sm.Ts[col][nc * 8];
        }
    } else {
        // ---- q/k: LDS transpose [row][col] -> coalesced f16x8 stores ----
        __syncthreads();
        const float scl = (s == 0) ? QSCL : 1.0f;
        #pragma unroll
        for (int t = 0; t < 8; t++)
            #pragma unroll
            for (int mi = 0; mi < 2; mi++)
                #pragma unroll
                for (int r = 0; r < 4; r++)
                    sm.Ts2[w * 32 + mi * 16 + quad * 4 + r][t * 16 + cl] =
                        (_Float16)(acc[mi][t][r] * scl);
        __syncthreads();
        _Float16* dst = (s == 0) ? qh : kh;
        const int colbase = bn * 128 - s * 384;  // 0,128,256
        #pragma unroll
        for (int i = 0; i < 8; i++) {
            const int c = i * 256 + tid;         // 0..2047 chunks of 8
            const int row = c >> 4, ch = c & 15;
            const int gcol = colbase + ch * 8;   // multiple of 8; 48=6x8 -> no straddle
            const int head = gcol / 48, d = gcol - head * 48;
            const int bh = b * 8 + head;
            *(f16x8*)&dst[(size_t)(bh * 2048 + n0 + row) * 48 + d] =
                *(const f16x8*)&sm.Ts2[row][ch * 8];
        }
    }
}

// ---------------------------------------------------------------------------
// Flash attention (R18): LDS-staged, double-buffered, ONE barrier per tile.
// 32x32x16 f16 MFMA, no-max softmax with raw v_exp_f32 + v_cvt_pkrtz,
// register-P (global V already kappa-permuted), l via ones-row 48.
// Strides 56/72: every hot ds_read/ds_write_b128 16B-aligned.
// ---------------------------------------------------------------------------
#define KS_S 56   // 112 B stride: 16B-aligned b128 accesses
#define VS_S 72   // 144 B stride: 16B-aligned b128 accesses

union AttnSmem {
    struct {
        _Float16 Ks[2][64][KS_S];    // [buf][key][dh]       14336 B
        _Float16 Vts[2][64][VS_S];   // [buf][dh'][slot]     18432 B; row 48 ones
    } a;                             // 32768 B
    _Float16 Ot[128][58];            // epilogue transpose   14848 B
};

__global__ __launch_bounds__(256) void attn_f16(const _Float16* __restrict__ qh,
                                                const _Float16* __restrict__ kh,
                                                const _Float16* __restrict__ vt,
                                                _Float16* __restrict__ ab)
{
    __shared__ AttnSmem sm;
    const int tid = threadIdx.x;
    const int w = tid >> 6, lane = tid & 63, ln = lane & 31, h = lane >> 5;
    const int bh = blockIdx.x, qt = blockIdx.y;

    // one-time: Vts rows 48..63 for BOTH buffers (48 = ones for l, rest zero)
    for (int i = tid; i < 2 * 16 * VS_S; i += 256) {
        const int bi = i / (16 * VS_S), j = i - bi * (16 * VS_S);
        const int r = 48 + j / VS_S, c = j - (j / VS_S) * VS_S;
        sm.a.Vts[bi][r][c] = (r == 48) ? (_Float16)1.0f : (_Float16)0.0f;
    }

    // Q B-frags (3, dh = 16i + 8h + 0..7), query = qt*128 + w*32 + ln
    f16x8 qf[3];
    {
        const _Float16* qp = qh + (size_t)(bh * 2048 + qt * 128 + w * 32 + ln) * 48 + 8 * h;
        qf[0] = *(const f16x8*)qp;
        qf[1] = *(const f16x8*)(qp + 16);
        qf[2] = *(const f16x8*)(qp + 32);
    }

    f32x16 o0, o1;
    #pragma unroll
    for (int r = 0; r < 16; r++) { o0[r] = 0.f; o1[r] = 0.f; }

    const _Float16* kbase = kh + (size_t)bh * 2048 * 48;
    const _Float16* vbase = vt + (size_t)bh * 48 * 2048;

    // staging decomposition: K = 64 rows x 6 chunks = 384; V = 48 rows x 8 = 384
    const int kr0 = tid / 6,        kc0 = (tid % 6) * 8;
    const int kid1 = tid + 256;
    const int kr1 = kid1 / 6,       kc1 = (kid1 % 6) * 8;
    const int vr0 = tid >> 3,       vc0 = (tid & 7) * 8;   // rows 0..31
    const int vr1 = vr0 + 32;                              // rows 32..47 (tid<128)
    const _Float16* ks0 = kbase + (size_t)kr0 * 48 + kc0;
    const _Float16* ks1 = kbase + (size_t)kr1 * 48 + kc1;
    const _Float16* vs0 = vbase + (size_t)vr0 * 2048 + vc0;
    const _Float16* vs1 = vbase + (size_t)vr1 * 2048 + vc0;

    f16x8 rk0 = *(const f16x8*)ks0;
    f16x8 rv0 = *(const f16x8*)vs0;
    f16x8 rk1, rv1;
    if (tid < 128) { rk1 = *(const f16x8*)ks1; rv1 = *(const f16x8*)vs1; }

    for (int t = 0; t < 32; ++t) {
        _Float16 (*Ksb)[KS_S] = sm.a.Ks[t & 1];
        _Float16 (*Vtb)[VS_S] = sm.a.Vts[t & 1];

        // ---- stage regs -> LDS[buf]: contiguous b128 writes ----
        *(f16x8*)&Ksb[kr0][kc0] = rk0;
        *(f16x8*)&Vtb[vr0][vc0] = rv0;
        if (tid < 128) {
            *(f16x8*)&Ksb[kr1][kc1] = rk1;
            *(f16x8*)&Vtb[vr1][vc0] = rv1;
        }
        __syncthreads();   // single barrier/tile: dbuf covers write-after-read

        // ---- prefetch next tile into regs (in flight across compute) ----
        if (t < 31) {
            const int off = (t + 1) * 64;
            rk0 = *(const f16x8*)(ks0 + (size_t)off * 48);
            rv0 = *(const f16x8*)(vs0 + off);
            if (tid < 128) {
                rk1 = *(const f16x8*)(ks1 + (size_t)off * 48);
                rv1 = *(const f16x8*)(vs1 + off);
            }
        }

        // ---- S^T = K.Q^T : C[key][query] ----
        f32x16 s0, s1;
        #pragma unroll
        for (int r = 0; r < 16; r++) { s0[r] = 0.f; s1[r] = 0.f; }
        __builtin_amdgcn_s_setprio(1);
        #pragma unroll
        for (int i = 0; i < 3; i++) {
            const f16x8 ka0 = *(const f16x8*)&Ksb[ln][16 * i + 8 * h];
            s0 = __builtin_amdgcn_mfma_f32_32x32x16_f16(ka0, qf[i], s0, 0, 0, 0);
            const f16x8 ka1 = *(const f16x8*)&Ksb[32 + ln][16 * i + 8 * h];
            s1 = __builtin_amdgcn_mfma_f32_32x32x16_f16(ka1, qf[i], s1, 0, 0, 0);
        }
        __builtin_amdgcn_s_setprio(0);

        // ---- P = exp2(S^T): raw v_exp_f32 + packed cvt (v_cvt_pkrtz) ----
        f16x8 pbf[4];
        f16x2* pp = (f16x2*)pbf;   // pp[4c + m] = pbf[c] halves
        #pragma unroll
        for (int m = 0; m < 4; m++) {
            pp[m]      = cvt_pk_f16(
                __builtin_amdgcn_exp2f(s0[2 * m]),     __builtin_amdgcn_exp2f(s0[2 * m + 1]));
            pp[4 + m]  = cvt_pk_f16(
                __builtin_amdgcn_exp2f(s0[8 + 2 * m]), __builtin_amdgcn_exp2f(s0[9 + 2 * m]));
            pp[8 + m]  = cvt_pk_f16(
                __builtin_amdgcn_exp2f(s1[2 * m]),     __builtin_amdgcn_exp2f(s1[2 * m + 1]));
            pp[12 + m] = cvt_pk_f16(
                __builtin_amdgcn_exp2f(s1[8 + 2 * m]), __builtin_amdgcn_exp2f(s1[9 + 2 * m]));
        }

        // ---- O^T += V^T.P^T (ones row 48 accumulates l into o1[8]@h=0) ----
        __builtin_amdgcn_s_setprio(1);
        #pragma unroll
        for (int c = 0; c < 4; c++) {
            const f16x8 av0 = *(const f16x8*)&Vtb[ln][16 * c + 8 * h];
            o0 = __builtin_amdgcn_mfma_f32_32x32x16_f16(av0, pbf[c], o0, 0, 0, 0);
            const f16x8 av1 = *(const f16x8*)&Vtb[32 + ln][16 * c + 8 * h];
            o1 = __builtin_amdgcn_mfma_f32_32x32x16_f16(av1, pbf[c], o1, 0, 0, 0);
        }
        __builtin_amdgcn_s_setprio(0);
    }

    // ---- l(q) = O^T row 48 = o1 reg 8 on h=0 lanes (their query = ln) ----
    const float lr  = __shfl(o1[8], ln);
    const float inv = 1.f / lr;

    // ---- epilogue: O^T -> LDS transpose -> coalesced stores ----
    __syncthreads();
    #pragma unroll
    for (int r = 0; r < 16; r++)
        sm.Ot[w * 32 + ln][(r & 3) + 8 * (r >> 2) + 4 * h] = (_Float16)(o0[r] * inv);
    #pragma unroll
    for (int r = 0; r < 8; r++)
        sm.Ot[w * 32 + ln][32 + (r & 3) + 8 * (r >> 2) + 4 * h] = (_Float16)(o1[r] * inv);
    __syncthreads();
    const int b = bh >> 3, hd = bh & 7;
    #pragma unroll
    for (int i = 0; i < 3; i++) {
        const int c2 = i * 256 + tid;
        const int row = c2 / 6, ch = c2 % 6;
        const int q = qt * 128 + row;
        *(f16x8*)&ab[(size_t)(b * 2048 + q) * 384 + hd * 48 + ch * 8] =
            *(const f16x8*)&sm.Ot[row][ch * 8];
    }
}

// ---------------------------------------------------------------------------
// Proj GEMM: A = ab[8192][384] f16, Bt = wprojt[384][384] f16, +bias -> fp32
// 64x64 tile, BK=64, padded LDS, reg-prefetch.
// ---------------------------------------------------------------------------
__global__ __launch_bounds__(256) void proj_f16(const _Float16* __restrict__ A,
                                                const _Float16* __restrict__ Bt,
                                                const float* __restrict__ bias,
                                                float* __restrict__ out)
{
    __shared__ _Float16 As[64][72];
    __shared__ _Float16 Bs[64][72];
    const int tid = threadIdx.x;
    const int w = tid >> 6, lane = tid & 63, cl = lane & 15, quad = lane >> 4;
    const int bm = blockIdx.x, bn = blockIdx.y;

    f32x4 acc[4];
    const f32x4 z4 = {0.f, 0.f, 0.f, 0.f};
    #pragma unroll
    for (int t = 0; t < 4; t++) acc[t] = z4;

    const int ar = tid >> 3, ac = (tid & 7) * 8;
    const _Float16* Ag = A  + (size_t)(bm * 64 + ar) * 384 + ac;
    const _Float16* Bg = Bt + (size_t)(bn * 64 + ar) * 384 + ac;

    f16x8 pa[2], pb[2];
    #pragma unroll
    for (int j = 0; j < 2; j++) {
        pa[j] = *(const f16x8*)(Ag + (size_t)(32 * j) * 384);
        pb[j] = *(const f16x8*)(Bg + (size_t)(32 * j) * 384);
    }

    for (int k0 = 0; k0 < 384; k0 += 64) {
        __syncthreads();
        #pragma unroll
        for (int j = 0; j < 2; j++) {
            *(f16x8*)&As[ar + 32 * j][ac] = pa[j];
            *(f16x8*)&Bs[ar + 32 * j][ac] = pb[j];
        }
        __syncthreads();
        if (k0 + 64 < 384) {
            #pragma unroll
            for (int j = 0; j < 2; j++) {
                pa[j] = *(const f16x8*)(Ag + (size_t)(32 * j) * 384 + k0 + 64);
                pb[j] = *(const f16x8*)(Bg + (size_t)(32 * j) * 384 + k0 + 64);
            }
        }
        #pragma unroll
        for (int kh2 = 0; kh2 < 2; kh2++) {
            const f16x8 af = *(const f16x8*)&As[w * 16 + cl][kh2 * 32 + quad * 8];
            #pragma unroll
            for (int t = 0; t < 4; t++) {
                const f16x8 bf = *(const f16x8*)&Bs[t * 16 + cl][kh2 * 32 + quad * 8];
                acc[t] = __builtin_amdgcn_mfma_f32_16x16x32_f16(af, bf, acc[t], 0, 0, 0);
            }
        }
    }

    #pragma unroll
    for (int t = 0; t < 4; t++) {
        const int col = bn * 64 + t * 16 + cl;
        const float bv = bias[col];
        #pragma unroll
        for (int r = 0; r < 4; r++) {
            const int row = bm * 64 + w * 16 + quad * 4 + r;
            out[(size_t)row * 384 + col] = acc[t][r] + bv;
        }
    }
}

// ---------------------------------------------------------------------------
extern "C" void kernel_launch(void* const* d_in, const int* in_sizes, int n_in,
                              void* d_out, int out_size, void* d_ws, size_t ws_size,
                              hipStream_t stream) {
    const float* x     = (const float*)d_in[0];  // [4,2048,384]
    const float* Wqkv  = (const float*)d_in[1];  // [384,1152]
    const float* Wproj = (const float*)d_in[2];  // [384,384]
    const float* bproj = (const float*)d_in[3];  // [384]
    float* out = (float*)d_out;

    char* ws = (char*)d_ws;
    _Float16* xh     = (_Float16*)(ws + 0);          // 8192*384*2  = 6,291,456
    _Float16* wqkvt  = (_Float16*)(ws + 6291456);    // 1152*384*2  =   884,736
    _Float16* wprojt = (_Float16*)(ws + 7176192);    // 384*384*2   =   294,912
    _Float16* qh     = (_Float16*)(ws + 7471104);    // 32*2048*48*2 = 6,291,456
    _Float16* kh     = (_Float16*)(ws + 13762560);   // 6,291,456
    _Float16* vt     = (_Float16*)(ws + 20054016);   // 6,291,456
    _Float16* ab     = (_Float16*)(ws + 26345472);   // 6,291,456
    // total 32,636,928 B

    prep<<<400, 256, 0, stream>>>((const float4*)x, Wqkv, Wproj,
                                  (f16x4*)xh, wqkvt, wprojt);
    qkv_f16<<<dim3(64, 9), 256, 0, stream>>>(xh, wqkvt, qh, kh, vt);
    attn_f16<<<dim3(32, 16), 256, 0, stream>>>(qh, kh, vt, ab);
    proj_f16<<<dim3(128, 6), 256, 0, stream>>>(ab, wprojt, bproj, out);
}

// Round 6
// 130.155 us; speedup vs baseline: 1.6677x; 1.0240x over previous
//
#include <hip/hip_runtime.h>
#include <hip/hip_bf16.h>

// Attention B=4,N=2048,D=384,H=8,DH=48 — Round 19:
//  - attn: 512-thread blocks, in-block K-split. Wave-group g in {0,1} handles
//    keys [g*1024, g*1024+1024) for the SAME 128 queries; each group has its
//    own double-buffered K/V LDS (64 KiB total -> still 2 blocks/CU, now
//    4 waves/SIMD). 16 barrier iterations instead of 32. Partial O + l
//    combined in-block via LDS f32 (reuses dead K/V region) — no HBM
//    partials, no combine kernel (R15's failure mode avoided).
//    Kept from R18: raw v_exp_f32, packed cvt_pkrtz, ones-row l, aligned
//    strides 56/72, setprio, pre-permuted V.
//  - qkv/prep/proj unchanged.

typedef _Float16 f16x8 __attribute__((ext_vector_type(8)));
typedef _Float16 f16x4 __attribute__((ext_vector_type(4)));
typedef _Float16 f16x2 __attribute__((ext_vector_type(2)));
typedef float    f32x4 __attribute__((ext_vector_type(4)));
typedef float    f32x16 __attribute__((ext_vector_type(16)));

// scale * log2(e) = 48^-0.5 * 1.4426950408889634
#define QSCL 0.20822035963448658f

// packed f32x2 -> f16x2 convert (cvt_pkrtz returns __fp16x2; bitcast to f16x2)
static __device__ __forceinline__ f16x2 cvt_pk_f16(float a, float b) {
    return __builtin_bit_cast(f16x2, __builtin_amdgcn_cvt_pkrtz(a, b));
}

// ---------------------------------------------------------------------------
// prep: blocks 0..143 transpose weights (LDS-tiled); 144..399 convert x->f16
// ---------------------------------------------------------------------------
__global__ __launch_bounds__(256) void prep(const float4* __restrict__ x,
                                            const float* __restrict__ wq,
                                            const float* __restrict__ wp,
                                            f16x4* __restrict__ xh4,
                                            _Float16* __restrict__ wqt,
                                            _Float16* __restrict__ wpt)
{
    __shared__ _Float16 t[64][65];
    const int blk = blockIdx.x, tid = threadIdx.x;
    if (blk < 144) {
        const float* src; _Float16* dst; int Nn, k0, n0;
        if (blk < 108) {            // Wqkv: 6 k-tiles x 18 n-tiles
            src = wq; dst = wqt; Nn = 1152;
            k0 = (blk % 6) * 64; n0 = (blk / 6) * 64;
        } else {                    // Wproj: 6 x 6
            const int b2 = blk - 108;
            src = wp; dst = wpt; Nn = 384;
            k0 = (b2 % 6) * 64; n0 = (b2 / 6) * 64;
        }
        #pragma unroll
        for (int i = 0; i < 16; i++) {
            const int id = tid + i * 256;
            const int k = id >> 6, n = id & 63;      // coalesced over n
            t[k][n] = (_Float16)src[(size_t)(k0 + k) * Nn + n0 + n];
        }
        __syncthreads();
        #pragma unroll
        for (int i = 0; i < 16; i++) {
            const int id = tid + i * 256;
            const int n = id >> 6, k = id & 63;      // coalesced over k
            dst[(size_t)(n0 + n) * 384 + k0 + k] = t[k][n];
        }
    } else {
        const int base = (blk - 144) * 3072;         // 256 blocks x 3072 = 786432
        #pragma unroll
        for (int r = 0; r < 12; r++) {
            const int j = base + r * 256 + tid;
            const float4 tt = x[j];
            f16x4 hh;
            hh[0] = (_Float16)tt.x; hh[1] = (_Float16)tt.y;
            hh[2] = (_Float16)tt.z; hh[3] = (_Float16)tt.w;
            xh4[j] = hh;
        }
    }
}

// ---------------------------------------------------------------------------
// QKV GEMM: A = xh[8192][384] f16, Bt = wqkvt[1152][384] f16.
// 128x128 tile, BK=32, padded LDS (stride 40), 16x16x32 MFMA, 4 waves,
// reg-prefetch. Epilogue via LDS transpose -> coalesced f16x8 stores.
// V epilogue stores the kappa-permuted token order (bits 2<->3 of token%16)
// so attn's PV A-fragments are contiguous f16x8 loads.
// ---------------------------------------------------------------------------
union QkvSmem {
    struct { _Float16 As[128][40]; _Float16 Bs[128][40]; } g;  // 20480 B
    _Float16 Ts[128][136];   // V transpose   [col][n]   34816 B
    _Float16 Ts2[128][136];  // q/k transpose [row][col] 34816 B
};

__global__ __launch_bounds__(256) void qkv_f16(const _Float16* __restrict__ A,
                                               const _Float16* __restrict__ Bt,
                                               _Float16* __restrict__ qh,
                                               _Float16* __restrict__ kh,
                                               _Float16* __restrict__ vt)
{
    __shared__ QkvSmem sm;
    const int tid = threadIdx.x;
    const int w = tid >> 6, lane = tid & 63, cl = lane & 15, quad = lane >> 4;
    const int bm = blockIdx.x, bn = blockIdx.y;

    f32x4 acc[2][8];
    const f32x4 z4 = {0.f, 0.f, 0.f, 0.f};
    #pragma unroll
    for (int mi = 0; mi < 2; mi++)
        #pragma unroll
        for (int t = 0; t < 8; t++) acc[mi][t] = z4;

    const int ar = tid >> 2, ac = (tid & 3) * 8;     // 512 chunks: 2/thread
    const _Float16* Ag = A  + (size_t)(bm * 128 + ar) * 384 + ac;
    const _Float16* Bg = Bt + (size_t)(bn * 128 + ar) * 384 + ac;

    f16x8 pa[2], pb[2];
    #pragma unroll
    for (int j = 0; j < 2; j++) {
        pa[j] = *(const f16x8*)(Ag + (size_t)(64 * j) * 384);
        pb[j] = *(const f16x8*)(Bg + (size_t)(64 * j) * 384);
    }

    for (int k0 = 0; k0 < 384; k0 += 32) {
        __syncthreads();
        #pragma unroll
        for (int j = 0; j < 2; j++) {
            *(f16x8*)&sm.g.As[ar + 64 * j][ac] = pa[j];
            *(f16x8*)&sm.g.Bs[ar + 64 * j][ac] = pb[j];
        }
        __syncthreads();
        if (k0 + 32 < 384) {
            #pragma unroll
            for (int j = 0; j < 2; j++) {
                pa[j] = *(const f16x8*)(Ag + (size_t)(64 * j) * 384 + k0 + 32);
                pb[j] = *(const f16x8*)(Bg + (size_t)(64 * j) * 384 + k0 + 32);
            }
        }
        f16x8 bf[8];
        #pragma unroll
        for (int t = 0; t < 8; t++)
            bf[t] = *(const f16x8*)&sm.g.Bs[t * 16 + cl][quad * 8];
        #pragma unroll
        for (int mi = 0; mi < 2; mi++) {
            const f16x8 af = *(const f16x8*)&sm.g.As[w * 32 + mi * 16 + cl][quad * 8];
            #pragma unroll
            for (int t = 0; t < 8; t++)
                acc[mi][t] = __builtin_amdgcn_mfma_f32_16x16x32_f16(af, bf[t], acc[mi][t], 0, 0, 0);
        }
    }

    const int s = (bn * 128) / 384;    // uniform per block (384 % 128 == 0)
    const int b  = (bm * 128) >> 11;
    const int n0 = (bm * 128) & 2047;
    if (s == 2) {
        // ---- V: LDS transpose [col][token'] with kappa perm on token%16 ----
        __syncthreads();
        const int qp = ((quad & 1) << 1) | (quad >> 1);   // swap bits of quad
        #pragma unroll
        for (int t = 0; t < 8; t++)
            #pragma unroll
            for (int mi = 0; mi < 2; mi++)
                #pragma unroll
                for (int r = 0; r < 4; r++)
                    sm.Ts[t * 16 + cl][w * 32 + mi * 16 + qp * 4 + r] =
                        (_Float16)acc[mi][t][r];
        __syncthreads();
        const int colbase = bn * 128 - 768;      // 0,128,256
        #pragma unroll
        for (int i = 0; i < 8; i++) {
            const int c = i * 256 + tid;         // 0..2047 chunks of 8
            const int col = c >> 4, nc = c & 15;
            const int gcol = colbase + col;
            const int head = gcol / 48, d = gcol - head * 48;
            const int bh = b * 8 + head;
            *(f16x8*)&vt[(size_t)(bh * 48 + d) * 2048 + n0 + nc * 8] =
                *(const f16x8*)&sm.Ts[col][nc * 8];
        }
    } else {
        // ---- q/k: LDS transpose [row][col] -> coalesced f16x8 stores ----
        __syncthreads();
        const float scl = (s == 0) ? QSCL : 1.0f;
        #pragma unroll
        for (int t = 0; t < 8; t++)
            #pragma unroll
            for (int mi = 0; mi < 2; mi++)
                #pragma unroll
                for (int r = 0; r < 4; r++)
                    sm.Ts2[w * 32 + mi * 16 + quad * 4 + r][t * 16 + cl] =
                        (_Float16)(acc[mi][t][r] * scl);
        __syncthreads();
        _Float16* dst = (s == 0) ? qh : kh;
        const int colbase = bn * 128 - s * 384;  // 0,128,256
        #pragma unroll
        for (int i = 0; i < 8; i++) {
            const int c = i * 256 + tid;         // 0..2047 chunks of 8
            const int row = c >> 4, ch = c & 15;
            const int gcol = colbase + ch * 8;   // multiple of 8; 48=6x8 -> no straddle
            const int head = gcol / 48, d = gcol - head * 48;
            const int bh = b * 8 + head;
            *(f16x8*)&dst[(size_t)(bh * 2048 + n0 + row) * 48 + d] =
                *(const f16x8*)&sm.Ts2[row][ch * 8];
        }
    }
}

// ---------------------------------------------------------------------------
// Flash attention (R19): 512 threads, in-block K-split (2 wave-groups x 1024
// keys), per-group double-buffered LDS, ONE barrier/tile, 16 tiles.
// 32x32x16 f16 MFMA, no-max softmax (raw v_exp_f32 + cvt_pkrtz), ones-row l.
// In-block f32 combine via LDS; epilogue transpose unchanged.
// ---------------------------------------------------------------------------
#define KS_S 56   // 112 B stride: 16B-aligned b128 accesses
#define VS_S 72   // 144 B stride: 16B-aligned b128 accesses

union AttnSmem {
    struct {
        _Float16 Ks[2][2][64][KS_S];    // [grp][buf][key][dh]    28672 B
        _Float16 Vts[2][2][64][VS_S];   // [grp][buf][dh'][slot]  36864 B
    } a;                                // 65536 B
    struct {
        float    Of[128][52];           // partial O^T (q-major)  26624 B
        float    lv[128];               // group-1 partial l        512 B
        _Float16 Ot[128][58];           // epilogue transpose     14848 B
    } e;                                // 41984 B
};

__global__ __launch_bounds__(512) void attn_f16(const _Float16* __restrict__ qh,
                                                const _Float16* __restrict__ kh,
                                                const _Float16* __restrict__ vt,
                                                _Float16* __restrict__ ab)
{
    __shared__ AttnSmem sm;
    const int tid = threadIdx.x;
    const int w = tid >> 6, lane = tid & 63, ln = lane & 31, h = lane >> 5;
    const int g = w >> 2, wg = w & 3;          // key-group, wave-in-group
    const int tid2 = tid & 255;                // group-local thread id
    const int bh = blockIdx.x, qt = blockIdx.y;

    // one-time: Vts rows 48..63 for both groups & buffers (48 = ones, rest 0)
    for (int i = tid; i < 2 * 2 * 16 * VS_S; i += 512) {
        const int gi = i / (2 * 16 * VS_S);
        const int j  = i - gi * (2 * 16 * VS_S);
        const int bi = j / (16 * VS_S);
        const int j2 = j - bi * (16 * VS_S);
        const int r = 48 + j2 / VS_S, c = j2 % VS_S;
        sm.a.Vts[gi][bi][r][c] = (r == 48) ? (_Float16)1.0f : (_Float16)0.0f;
    }

    // Q B-frags (3, dh = 16i + 8h + 0..7), query = qt*128 + wg*32 + ln
    f16x8 qf[3];
    {
        const _Float16* qp = qh + (size_t)(bh * 2048 + qt * 128 + wg * 32 + ln) * 48 + 8 * h;
        qf[0] = *(const f16x8*)qp;
        qf[1] = *(const f16x8*)(qp + 16);
        qf[2] = *(const f16x8*)(qp + 32);
    }

    f32x16 o0, o1;
    #pragma unroll
    for (int r = 0; r < 16; r++) { o0[r] = 0.f; o1[r] = 0.f; }

    // this group's key range: [g*1024, g*1024+1024)
    const _Float16* kbase = kh + (size_t)bh * 2048 * 48 + (size_t)g * 1024 * 48;
    const _Float16* vbase = vt + (size_t)bh * 48 * 2048 + g * 1024;

    // staging (per group, 256 threads): K = 64r x 6 chunks; V = 48r x 8 chunks
    const int kr0 = tid2 / 6,        kc0 = (tid2 % 6) * 8;
    const int kid1 = tid2 + 256;
    const int kr1 = kid1 / 6,        kc1 = (kid1 % 6) * 8;
    const int vr0 = tid2 >> 3,       vc0 = (tid2 & 7) * 8;   // rows 0..31
    const int vr1 = vr0 + 32;                                // rows 32..47 (tid2<128)
    const _Float16* ks0 = kbase + (size_t)kr0 * 48 + kc0;
    const _Float16* ks1 = kbase + (size_t)kr1 * 48 + kc1;
    const _Float16* vs0 = vbase + (size_t)vr0 * 2048 + vc0;
    const _Float16* vs1 = vbase + (size_t)vr1 * 2048 + vc0;

    f16x8 rk0 = *(const f16x8*)ks0;
    f16x8 rv0 = *(const f16x8*)vs0;
    f16x8 rk1, rv1;
    if (tid2 < 128) { rk1 = *(const f16x8*)ks1; rv1 = *(const f16x8*)vs1; }

    for (int t = 0; t < 16; ++t) {
        _Float16 (*Ksb)[KS_S] = sm.a.Ks[g][t & 1];
        _Float16 (*Vtb)[VS_S] = sm.a.Vts[g][t & 1];

        // ---- stage regs -> LDS[grp][buf]: contiguous b128 writes ----
        *(f16x8*)&Ksb[kr0][kc0] = rk0;
        *(f16x8*)&Vtb[vr0][vc0] = rv0;
        if (tid2 < 128) {
            *(f16x8*)&Ksb[kr1][kc1] = rk1;
            *(f16x8*)&Vtb[vr1][vc0] = rv1;
        }
        __syncthreads();   // both groups in lockstep; dbuf covers WAR

        // ---- prefetch next tile into regs ----
        if (t < 15) {
            const int off = (t + 1) * 64;
            rk0 = *(const f16x8*)(ks0 + (size_t)off * 48);
            rv0 = *(const f16x8*)(vs0 + off);
            if (tid2 < 128) {
                rk1 = *(const f16x8*)(ks1 + (size_t)off * 48);
                rv1 = *(const f16x8*)(vs1 + off);
            }
        }

        // ---- S^T = K.Q^T : C[key][query] ----
        f32x16 s0, s1;
        #pragma unroll
        for (int r = 0; r < 16; r++) { s0[r] = 0.f; s1[r] = 0.f; }
        __builtin_amdgcn_s_setprio(1);
        #pragma unroll
        for (int i = 0; i < 3; i++) {
            const f16x8 ka0 = *(const f16x8*)&Ksb[ln][16 * i + 8 * h];
            s0 = __builtin_amdgcn_mfma_f32_32x32x16_f16(ka0, qf[i], s0, 0, 0, 0);
            const f16x8 ka1 = *(const f16x8*)&Ksb[32 + ln][16 * i + 8 * h];
            s1 = __builtin_amdgcn_mfma_f32_32x32x16_f16(ka1, qf[i], s1, 0, 0, 0);
        }
        __builtin_amdgcn_s_setprio(0);

        // ---- P = exp2(S^T): raw v_exp_f32 + packed cvt ----
        f16x8 pbf[4];
        f16x2* pp = (f16x2*)pbf;
        #pragma unroll
        for (int m = 0; m < 4; m++) {
            pp[m]      = cvt_pk_f16(
                __builtin_amdgcn_exp2f(s0[2 * m]),     __builtin_amdgcn_exp2f(s0[2 * m + 1]));
            pp[4 + m]  = cvt_pk_f16(
                __builtin_amdgcn_exp2f(s0[8 + 2 * m]), __builtin_amdgcn_exp2f(s0[9 + 2 * m]));
            pp[8 + m]  = cvt_pk_f16(
                __builtin_amdgcn_exp2f(s1[2 * m]),     __builtin_amdgcn_exp2f(s1[2 * m + 1]));
            pp[12 + m] = cvt_pk_f16(
                __builtin_amdgcn_exp2f(s1[8 + 2 * m]), __builtin_amdgcn_exp2f(s1[9 + 2 * m]));
        }

        // ---- O^T += V^T.P^T (ones row 48 accumulates l into o1[8]@h=0) ----
        __builtin_amdgcn_s_setprio(1);
        #pragma unroll
        for (int c = 0; c < 4; c++) {
            const f16x8 av0 = *(const f16x8*)&Vtb[ln][16 * c + 8 * h];
            o0 = __builtin_amdgcn_mfma_f32_32x32x16_f16(av0, pbf[c], o0, 0, 0, 0);
            const f16x8 av1 = *(const f16x8*)&Vtb[32 + ln][16 * c + 8 * h];
            o1 = __builtin_amdgcn_mfma_f32_32x32x16_f16(av1, pbf[c], o1, 0, 0, 0);
        }
        __builtin_amdgcn_s_setprio(0);
    }

    // own-group l(q=ln) lives on h=0 lanes in o1[8]
    const float lown = __shfl(o1[8], ln);

    __syncthreads();   // all compute done before Of overwrites K/V region

    const int row = wg * 32 + ln;
    if (g == 1) {
        // write partial O^T (f32) + partial l
        #pragma unroll
        for (int q4 = 0; q4 < 4; q4++) {
            f32x4 tq = { o0[4 * q4], o0[4 * q4 + 1], o0[4 * q4 + 2], o0[4 * q4 + 3] };
            *(f32x4*)&sm.e.Of[row][8 * q4 + 4 * h] = tq;
        }
        #pragma unroll
        for (int q4 = 0; q4 < 2; q4++) {
            f32x4 tq = { o1[4 * q4], o1[4 * q4 + 1], o1[4 * q4 + 2], o1[4 * q4 + 3] };
            *(f32x4*)&sm.e.Of[row][32 + 8 * q4 + 4 * h] = tq;
        }
        if (h == 0) sm.e.lv[row] = o1[8];
    }
    __syncthreads();
    if (g == 0) {
        // add group-1 partials, normalize, transpose to Ot
        #pragma unroll
        for (int q4 = 0; q4 < 4; q4++) {
            const f32x4 tq = *(const f32x4*)&sm.e.Of[row][8 * q4 + 4 * h];
            o0[4 * q4] += tq[0]; o0[4 * q4 + 1] += tq[1];
            o0[4 * q4 + 2] += tq[2]; o0[4 * q4 + 3] += tq[3];
        }
        #pragma unroll
        for (int q4 = 0; q4 < 2; q4++) {
            const f32x4 tq = *(const f32x4*)&sm.e.Of[row][32 + 8 * q4 + 4 * h];
            o1[4 * q4] += tq[0]; o1[4 * q4 + 1] += tq[1];
            o1[4 * q4 + 2] += tq[2]; o1[4 * q4 + 3] += tq[3];
        }
        const float inv = 1.f / (lown + sm.e.lv[row]);
        #pragma unroll
        for (int r = 0; r < 16; r++)
            sm.e.Ot[row][(r & 3) + 8 * (r >> 2) + 4 * h] = (_Float16)(o0[r] * inv);
        #pragma unroll
        for (int r = 0; r < 8; r++)
            sm.e.Ot[row][32 + (r & 3) + 8 * (r >> 2) + 4 * h] = (_Float16)(o1[r] * inv);
    }
    __syncthreads();
    if (g == 0) {
        const int b = bh >> 3, hd = bh & 7;
        #pragma unroll
        for (int i = 0; i < 3; i++) {
            const int c2 = i * 256 + tid;
            const int rw = c2 / 6, ch = c2 % 6;
            const int q = qt * 128 + rw;
            *(f16x8*)&ab[(size_t)(b * 2048 + q) * 384 + hd * 48 + ch * 8] =
                *(const f16x8*)&sm.e.Ot[rw][ch * 8];
        }
    }
}

// ---------------------------------------------------------------------------
// Proj GEMM: A = ab[8192][384] f16, Bt = wprojt[384][384] f16, +bias -> fp32
// 64x64 tile, BK=64, padded LDS, reg-prefetch.
// ---------------------------------------------------------------------------
__global__ __launch_bounds__(256) void proj_f16(const _Float16* __restrict__ A,
                                                const _Float16* __restrict__ Bt,
                                                const float* __restrict__ bias,
                                                float* __restrict__ out)
{
    __shared__ _Float16 As[64][72];
    __shared__ _Float16 Bs[64][72];
    const int tid = threadIdx.x;
    const int w = tid >> 6, lane = tid & 63, cl = lane & 15, quad = lane >> 4;
    const int bm = blockIdx.x, bn = blockIdx.y;

    f32x4 acc[4];
    const f32x4 z4 = {0.f, 0.f, 0.f, 0.f};
    #pragma unroll
    for (int t = 0; t < 4; t++) acc[t] = z4;

    const int ar = tid >> 3, ac = (tid & 7) * 8;
    const _Float16* Ag = A  + (size_t)(bm * 64 + ar) * 384 + ac;
    const _Float16* Bg = Bt + (size_t)(bn * 64 + ar) * 384 + ac;

    f16x8 pa[2], pb[2];
    #pragma unroll
    for (int j = 0; j < 2; j++) {
        pa[j] = *(const f16x8*)(Ag + (size_t)(32 * j) * 384);
        pb[j] = *(const f16x8*)(Bg + (size_t)(32 * j) * 384);
    }

    for (int k0 = 0; k0 < 384; k0 += 64) {
        __syncthreads();
        #pragma unroll
        for (int j = 0; j < 2; j++) {
            *(f16x8*)&As[ar + 32 * j][ac] = pa[j];
            *(f16x8*)&Bs[ar + 32 * j][ac] = pb[j];
        }
        __syncthreads();
        if (k0 + 64 < 384) {
            #pragma unroll
            for (int j = 0; j < 2; j++) {
                pa[j] = *(const f16x8*)(Ag + (size_t)(32 * j) * 384 + k0 + 64);
                pb[j] = *(const f16x8*)(Bg + (size_t)(32 * j) * 384 + k0 + 64);
            }
        }
        #pragma unroll
        for (int kh2 = 0; kh2 < 2; kh2++) {
            const f16x8 af = *(const f16x8*)&As[w * 16 + cl][kh2 * 32 + quad * 8];
            #pragma unroll
            for (int t = 0; t < 4; t++) {
                const f16x8 bf = *(const f16x8*)&Bs[t * 16 + cl][kh2 * 32 + quad * 8];
                acc[t] = __builtin_amdgcn_mfma_f32_16x16x32_f16(af, bf, acc[t], 0, 0, 0);
            }
        }
    }

    #pragma unroll
    for (int t = 0; t < 4; t++) {
        const int col = bn * 64 + t * 16 + cl;
        const float bv = bias[col];
        #pragma unroll
        for (int r = 0; r < 4; r++) {
            const int row = bm * 64 + w * 16 + quad * 4 + r;
            out[(size_t)row * 384 + col] = acc[t][r] + bv;
        }
    }
}

// ---------------------------------------------------------------------------
extern "C" void kernel_launch(void* const* d_in, const int* in_sizes, int n_in,
                              void* d_out, int out_size, void* d_ws, size_t ws_size,
                              hipStream_t stream) {
    const float* x     = (const float*)d_in[0];  // [4,2048,384]
    const float* Wqkv  = (const float*)d_in[1];  // [384,1152]
    const float* Wproj = (const float*)d_in[2];  // [384,384]
    const float* bproj = (const float*)d_in[3];  // [384]
    float* out = (float*)d_out;

    char* ws = (char*)d_ws;
    _Float16* xh     = (_Float16*)(ws + 0);          // 8192*384*2  = 6,291,456
    _Float16* wqkvt  = (_Float16*)(ws + 6291456);    // 1152*384*2  =   884,736
    _Float16* wprojt = (_Float16*)(ws + 7176192);    // 384*384*2   =   294,912
    _Float16* qh     = (_Float16*)(ws + 7471104);    // 32*2048*48*2 = 6,291,456
    _Float16* kh     = (_Float16*)(ws + 13762560);   // 6,291,456
    _Float16* vt     = (_Float16*)(ws + 20054016);   // 6,291,456
    _Float16* ab     = (_Float16*)(ws + 26345472);   // 6,291,456
    // total 32,636,928 B

    prep<<<400, 256, 0, stream>>>((const float4*)x, Wqkv, Wproj,
                                  (f16x4*)xh, wqkvt, wprojt);
    qkv_f16<<<dim3(64, 9), 256, 0, stream>>>(xh, wqkvt, qh, kh, vt);
    attn_f16<<<dim3(32, 16), 512, 0, stream>>>(qh, kh, vt, ab);
    proj_f16<<<dim3(128, 6), 256, 0, stream>>>(ab, wprojt, bproj, out);
}

// Round 7
// 126.742 us; speedup vs baseline: 1.7126x; 1.0269x over previous
//
#include <hip/hip_runtime.h>
#include <hip/hip_bf16.h>

// Attention B=4,N=2048,D=384,H=8,DH=48 — Round 20:
//  - ALL hot kernels restructured to stage-ahead double-buffering with ONE
//    barrier per K-step: at iter t, stage tile t+1 (regs loaded at t-1) into
//    the other LDS buffer (overlaps compute), issue loads for t+2, compute
//    tile t, barrier. Removes the stage->drain->barrier->compute serial chain
//    that R19 counters showed as ~2500 stall cycles/iteration.
//  - attn: R19 in-block K-split structure kept (512 thr, 2 groups, in-block
//    combine), loop restructured as above.
//  - qkv: 2-barrier single-buffer -> 1-barrier dbuf (24 -> 12 barriers).
//  - proj: BK 64 -> 32, 1-barrier dbuf (12 iterations).
//  - prep unchanged. No numerics changes.

typedef _Float16 f16x8 __attribute__((ext_vector_type(8)));
typedef _Float16 f16x4 __attribute__((ext_vector_type(4)));
typedef _Float16 f16x2 __attribute__((ext_vector_type(2)));
typedef float    f32x4 __attribute__((ext_vector_type(4)));
typedef float    f32x16 __attribute__((ext_vector_type(16)));

// scale * log2(e) = 48^-0.5 * 1.4426950408889634
#define QSCL 0.20822035963448658f

// packed f32x2 -> f16x2 convert (cvt_pkrtz returns __fp16x2; bitcast to f16x2)
static __device__ __forceinline__ f16x2 cvt_pk_f16(float a, float b) {
    return __builtin_bit_cast(f16x2, __builtin_amdgcn_cvt_pkrtz(a, b));
}

// ---------------------------------------------------------------------------
// prep: blocks 0..143 transpose weights (LDS-tiled); 144..399 convert x->f16
// ---------------------------------------------------------------------------
__global__ __launch_bounds__(256) void prep(const float4* __restrict__ x,
                                            const float* __restrict__ wq,
                                            const float* __restrict__ wp,
                                            f16x4* __restrict__ xh4,
                                            _Float16* __restrict__ wqt,
                                            _Float16* __restrict__ wpt)
{
    __shared__ _Float16 t[64][65];
    const int blk = blockIdx.x, tid = threadIdx.x;
    if (blk < 144) {
        const float* src; _Float16* dst; int Nn, k0, n0;
        if (blk < 108) {            // Wqkv: 6 k-tiles x 18 n-tiles
            src = wq; dst = wqt; Nn = 1152;
            k0 = (blk % 6) * 64; n0 = (blk / 6) * 64;
        } else {                    // Wproj: 6 x 6
            const int b2 = blk - 108;
            src = wp; dst = wpt; Nn = 384;
            k0 = (b2 % 6) * 64; n0 = (b2 / 6) * 64;
        }
        #pragma unroll
        for (int i = 0; i < 16; i++) {
            const int id = tid + i * 256;
            const int k = id >> 6, n = id & 63;      // coalesced over n
            t[k][n] = (_Float16)src[(size_t)(k0 + k) * Nn + n0 + n];
        }
        __syncthreads();
        #pragma unroll
        for (int i = 0; i < 16; i++) {
            const int id = tid + i * 256;
            const int n = id >> 6, k = id & 63;      // coalesced over k
            dst[(size_t)(n0 + n) * 384 + k0 + k] = t[k][n];
        }
    } else {
        const int base = (blk - 144) * 3072;         // 256 blocks x 3072 = 786432
        #pragma unroll
        for (int r = 0; r < 12; r++) {
            const int j = base + r * 256 + tid;
            const float4 tt = x[j];
            f16x4 hh;
            hh[0] = (_Float16)tt.x; hh[1] = (_Float16)tt.y;
            hh[2] = (_Float16)tt.z; hh[3] = (_Float16)tt.w;
            xh4[j] = hh;
        }
    }
}

// ---------------------------------------------------------------------------
// QKV GEMM: A = xh[8192][384] f16, Bt = wqkvt[1152][384] f16.
// 128x128 tile, BK=32, stage-ahead dbuf, ONE barrier/iter (12 total),
// 16x16x32 MFMA, 4 waves. Epilogue via LDS transpose (V gets kappa perm).
// ---------------------------------------------------------------------------
union QkvSmem {
    struct { _Float16 As[2][128][40]; _Float16 Bs[2][128][40]; } g;  // 40960 B
    _Float16 Ts[128][136];   // V transpose   [col][n]   34816 B
    _Float16 Ts2[128][136];  // q/k transpose [row][col] 34816 B
};

__global__ __launch_bounds__(256) void qkv_f16(const _Float16* __restrict__ A,
                                               const _Float16* __restrict__ Bt,
                                               _Float16* __restrict__ qh,
                                               _Float16* __restrict__ kh,
                                               _Float16* __restrict__ vt)
{
    __shared__ QkvSmem sm;
    const int tid = threadIdx.x;
    const int w = tid >> 6, lane = tid & 63, cl = lane & 15, quad = lane >> 4;
    const int bm = blockIdx.x, bn = blockIdx.y;

    f32x4 acc[2][8];
    const f32x4 z4 = {0.f, 0.f, 0.f, 0.f};
    #pragma unroll
    for (int mi = 0; mi < 2; mi++)
        #pragma unroll
        for (int t = 0; t < 8; t++) acc[mi][t] = z4;

    const int ar = tid >> 2, ac = (tid & 3) * 8;     // 512 chunks: 2/thread
    const _Float16* Ag = A  + (size_t)(bm * 128 + ar) * 384 + ac;
    const _Float16* Bg = Bt + (size_t)(bn * 128 + ar) * 384 + ac;

    f16x8 pa[2], pb[2];
    #pragma unroll
    for (int j = 0; j < 2; j++) {
        pa[j] = *(const f16x8*)(Ag + (size_t)(64 * j) * 384);
        pb[j] = *(const f16x8*)(Bg + (size_t)(64 * j) * 384);
    }
    // prologue: stage k0=0 into buf0, then load k0=32
    #pragma unroll
    for (int j = 0; j < 2; j++) {
        *(f16x8*)&sm.g.As[0][ar + 64 * j][ac] = pa[j];
        *(f16x8*)&sm.g.Bs[0][ar + 64 * j][ac] = pb[j];
    }
    #pragma unroll
    for (int j = 0; j < 2; j++) {
        pa[j] = *(const f16x8*)(Ag + (size_t)(64 * j) * 384 + 32);
        pb[j] = *(const f16x8*)(Bg + (size_t)(64 * j) * 384 + 32);
    }
    __syncthreads();

    for (int it = 0; it < 12; ++it) {
        // stage next tile (regs from iter it-1) into other buffer; load it+2
        if (it < 11) {
            #pragma unroll
            for (int j = 0; j < 2; j++) {
                *(f16x8*)&sm.g.As[(it + 1) & 1][ar + 64 * j][ac] = pa[j];
                *(f16x8*)&sm.g.Bs[(it + 1) & 1][ar + 64 * j][ac] = pb[j];
            }
            if (it < 10) {
                const int off = (it + 2) * 32;
                #pragma unroll
                for (int j = 0; j < 2; j++) {
                    pa[j] = *(const f16x8*)(Ag + (size_t)(64 * j) * 384 + off);
                    pb[j] = *(const f16x8*)(Bg + (size_t)(64 * j) * 384 + off);
                }
            }
        }
        // compute on buf[it&1]
        f16x8 bf[8];
        #pragma unroll
        for (int t = 0; t < 8; t++)
            bf[t] = *(const f16x8*)&sm.g.Bs[it & 1][t * 16 + cl][quad * 8];
        #pragma unroll
        for (int mi = 0; mi < 2; mi++) {
            const f16x8 af = *(const f16x8*)&sm.g.As[it & 1][w * 32 + mi * 16 + cl][quad * 8];
            #pragma unroll
            for (int t = 0; t < 8; t++)
                acc[mi][t] = __builtin_amdgcn_mfma_f32_16x16x32_f16(af, bf[t], acc[mi][t], 0, 0, 0);
        }
        __syncthreads();
    }

    const int s = (bn * 128) / 384;    // uniform per block (384 % 128 == 0)
    const int b  = (bm * 128) >> 11;
    const int n0 = (bm * 128) & 2047;
    if (s == 2) {
        // ---- V: LDS transpose [col][token'] with kappa perm on token%16 ----
        const int qp = ((quad & 1) << 1) | (quad >> 1);   // swap bits of quad
        #pragma unroll
        for (int t = 0; t < 8; t++)
            #pragma unroll
            for (int mi = 0; mi < 2; mi++)
                #pragma unroll
                for (int r = 0; r < 4; r++)
                    sm.Ts[t * 16 + cl][w * 32 + mi * 16 + qp * 4 + r] =
                        (_Float16)acc[mi][t][r];
        __syncthreads();
        const int colbase = bn * 128 - 768;      // 0,128,256
        #pragma unroll
        for (int i = 0; i < 8; i++) {
            const int c = i * 256 + tid;         // 0..2047 chunks of 8
            const int col = c >> 4, nc = c & 15;
            const int gcol = colbase + col;
            const int head = gcol / 48, d = gcol - head * 48;
            const int bh = b * 8 + head;
            *(f16x8*)&vt[(size_t)(bh * 48 + d) * 2048 + n0 + nc * 8] =
                *(const f16x8*)&sm.Ts[col][nc * 8];
        }
    } else {
        // ---- q/k: LDS transpose [row][col] -> coalesced f16x8 stores ----
        const float scl = (s == 0) ? QSCL : 1.0f;
        #pragma unroll
        for (int t = 0; t < 8; t++)
            #pragma unroll
            for (int mi = 0; mi < 2; mi++)
                #pragma unroll
                for (int r = 0; r < 4; r++)
                    sm.Ts2[w * 32 + mi * 16 + quad * 4 + r][t * 16 + cl] =
                        (_Float16)(acc[mi][t][r] * scl);
        __syncthreads();
        _Float16* dst = (s == 0) ? qh : kh;
        const int colbase = bn * 128 - s * 384;  // 0,128,256
        #pragma unroll
        for (int i = 0; i < 8; i++) {
            const int c = i * 256 + tid;         // 0..2047 chunks of 8
            const int row = c >> 4, ch = c & 15;
            const int gcol = colbase + ch * 8;   // multiple of 8; 48=6x8 -> no straddle
            const int head = gcol / 48, d = gcol - head * 48;
            const int bh = b * 8 + head;
            *(f16x8*)&dst[(size_t)(bh * 2048 + n0 + row) * 48 + d] =
                *(const f16x8*)&sm.Ts2[row][ch * 8];
        }
    }
}

// ---------------------------------------------------------------------------
// Flash attention (R20): R19 structure (512 thr, in-block K-split, in-block
// combine) with stage-ahead dbuf: stage tile t+1 || compute tile t, ONE
// barrier at iteration end. 32x32x16 f16 MFMA, no-max softmax, ones-row l.
// ---------------------------------------------------------------------------
#define KS_S 56   // 112 B stride: 16B-aligned b128 accesses
#define VS_S 72   // 144 B stride: 16B-aligned b128 accesses

union AttnSmem {
    struct {
        _Float16 Ks[2][2][64][KS_S];    // [grp][buf][key][dh]    28672 B
        _Float16 Vts[2][2][64][VS_S];   // [grp][buf][dh'][slot]  36864 B
    } a;                                // 65536 B
    struct {
        float    Of[128][52];           // partial O^T (q-major)  26624 B
        float    lv[128];               // group-1 partial l        512 B
        _Float16 Ot[128][58];           // epilogue transpose     14848 B
    } e;                                // 41984 B
};

__global__ __launch_bounds__(512) void attn_f16(const _Float16* __restrict__ qh,
                                                const _Float16* __restrict__ kh,
                                                const _Float16* __restrict__ vt,
                                                _Float16* __restrict__ ab)
{
    __shared__ AttnSmem sm;
    const int tid = threadIdx.x;
    const int w = tid >> 6, lane = tid & 63, ln = lane & 31, h = lane >> 5;
    const int g = w >> 2, wg = w & 3;          // key-group, wave-in-group
    const int tid2 = tid & 255;                // group-local thread id
    const int bh = blockIdx.x, qt = blockIdx.y;

    // one-time: Vts rows 48..63 for both groups & buffers (48 = ones, rest 0)
    for (int i = tid; i < 2 * 2 * 16 * VS_S; i += 512) {
        const int gi = i / (2 * 16 * VS_S);
        const int j  = i - gi * (2 * 16 * VS_S);
        const int bi = j / (16 * VS_S);
        const int j2 = j - bi * (16 * VS_S);
        const int r = 48 + j2 / VS_S, c = j2 % VS_S;
        sm.a.Vts[gi][bi][r][c] = (r == 48) ? (_Float16)1.0f : (_Float16)0.0f;
    }

    // Q B-frags (3, dh = 16i + 8h + 0..7), query = qt*128 + wg*32 + ln
    f16x8 qf[3];
    {
        const _Float16* qp = qh + (size_t)(bh * 2048 + qt * 128 + wg * 32 + ln) * 48 + 8 * h;
        qf[0] = *(const f16x8*)qp;
        qf[1] = *(const f16x8*)(qp + 16);
        qf[2] = *(const f16x8*)(qp + 32);
    }

    f32x16 o0, o1;
    #pragma unroll
    for (int r = 0; r < 16; r++) { o0[r] = 0.f; o1[r] = 0.f; }

    // this group's key range: [g*1024, g*1024+1024)
    const _Float16* kbase = kh + (size_t)bh * 2048 * 48 + (size_t)g * 1024 * 48;
    const _Float16* vbase = vt + (size_t)bh * 48 * 2048 + g * 1024;

    // staging (per group, 256 threads): K = 64r x 6 chunks; V = 48r x 8 chunks
    const int kr0 = tid2 / 6,        kc0 = (tid2 % 6) * 8;
    const int kid1 = tid2 + 256;
    const int kr1 = kid1 / 6,        kc1 = (kid1 % 6) * 8;
    const int vr0 = tid2 >> 3,       vc0 = (tid2 & 7) * 8;   // rows 0..31
    const int vr1 = vr0 + 32;                                // rows 32..47 (tid2<128)
    const _Float16* ks0 = kbase + (size_t)kr0 * 48 + kc0;
    const _Float16* ks1 = kbase + (size_t)kr1 * 48 + kc1;
    const _Float16* vs0 = vbase + (size_t)vr0 * 2048 + vc0;
    const _Float16* vs1 = vbase + (size_t)vr1 * 2048 + vc0;

    f16x8 rk0 = *(const f16x8*)ks0;
    f16x8 rv0 = *(const f16x8*)vs0;
    f16x8 rk1, rv1;
    if (tid2 < 128) { rk1 = *(const f16x8*)ks1; rv1 = *(const f16x8*)vs1; }

    // prologue: stage tile0 into buf0; load tile1 into regs
    {
        _Float16 (*Ksb)[KS_S] = sm.a.Ks[g][0];
        _Float16 (*Vtb)[VS_S] = sm.a.Vts[g][0];
        *(f16x8*)&Ksb[kr0][kc0] = rk0;
        *(f16x8*)&Vtb[vr0][vc0] = rv0;
        if (tid2 < 128) {
            *(f16x8*)&Ksb[kr1][kc1] = rk1;
            *(f16x8*)&Vtb[vr1][vc0] = rv1;
        }
        rk0 = *(const f16x8*)(ks0 + (size_t)64 * 48);
        rv0 = *(const f16x8*)(vs0 + 64);
        if (tid2 < 128) {
            rk1 = *(const f16x8*)(ks1 + (size_t)64 * 48);
            rv1 = *(const f16x8*)(vs1 + 64);
        }
        __syncthreads();
    }

    for (int t = 0; t < 16; ++t) {
        // ---- stage tile t+1 into other buffer (overlaps compute); load t+2 ----
        if (t < 15) {
            _Float16 (*Ksn)[KS_S] = sm.a.Ks[g][(t + 1) & 1];
            _Float16 (*Vtn)[VS_S] = sm.a.Vts[g][(t + 1) & 1];
            *(f16x8*)&Ksn[kr0][kc0] = rk0;
            *(f16x8*)&Vtn[vr0][vc0] = rv0;
            if (tid2 < 128) {
                *(f16x8*)&Ksn[kr1][kc1] = rk1;
                *(f16x8*)&Vtn[vr1][vc0] = rv1;
            }
            if (t < 14) {
                const int off = (t + 2) * 64;
                rk0 = *(const f16x8*)(ks0 + (size_t)off * 48);
                rv0 = *(const f16x8*)(vs0 + off);
                if (tid2 < 128) {
                    rk1 = *(const f16x8*)(ks1 + (size_t)off * 48);
                    rv1 = *(const f16x8*)(vs1 + off);
                }
            }
        }

        _Float16 (*Ksb)[KS_S] = sm.a.Ks[g][t & 1];
        _Float16 (*Vtb)[VS_S] = sm.a.Vts[g][t & 1];

        // ---- S^T = K.Q^T : C[key][query] ----
        f32x16 s0, s1;
        #pragma unroll
        for (int r = 0; r < 16; r++) { s0[r] = 0.f; s1[r] = 0.f; }
        __builtin_amdgcn_s_setprio(1);
        #pragma unroll
        for (int i = 0; i < 3; i++) {
            const f16x8 ka0 = *(const f16x8*)&Ksb[ln][16 * i + 8 * h];
            s0 = __builtin_amdgcn_mfma_f32_32x32x16_f16(ka0, qf[i], s0, 0, 0, 0);
            const f16x8 ka1 = *(const f16x8*)&Ksb[32 + ln][16 * i + 8 * h];
            s1 = __builtin_amdgcn_mfma_f32_32x32x16_f16(ka1, qf[i], s1, 0, 0, 0);
        }
        __builtin_amdgcn_s_setprio(0);

        // ---- P = exp2(S^T): raw v_exp_f32 + packed cvt ----
        f16x8 pbf[4];
        f16x2* pp = (f16x2*)pbf;
        #pragma unroll
        for (int m = 0; m < 4; m++) {
            pp[m]      = cvt_pk_f16(
                __builtin_amdgcn_exp2f(s0[2 * m]),     __builtin_amdgcn_exp2f(s0[2 * m + 1]));
            pp[4 + m]  = cvt_pk_f16(
                __builtin_amdgcn_exp2f(s0[8 + 2 * m]), __builtin_amdgcn_exp2f(s0[9 + 2 * m]));
            pp[8 + m]  = cvt_pk_f16(
                __builtin_amdgcn_exp2f(s1[2 * m]),     __builtin_amdgcn_exp2f(s1[2 * m + 1]));
            pp[12 + m] = cvt_pk_f16(
                __builtin_amdgcn_exp2f(s1[8 + 2 * m]), __builtin_amdgcn_exp2f(s1[9 + 2 * m]));
        }

        // ---- O^T += V^T.P^T (ones row 48 accumulates l into o1[8]@h=0) ----
        __builtin_amdgcn_s_setprio(1);
        #pragma unroll
        for (int c = 0; c < 4; c++) {
            const f16x8 av0 = *(const f16x8*)&Vtb[ln][16 * c + 8 * h];
            o0 = __builtin_amdgcn_mfma_f32_32x32x16_f16(av0, pbf[c], o0, 0, 0, 0);
            const f16x8 av1 = *(const f16x8*)&Vtb[32 + ln][16 * c + 8 * h];
            o1 = __builtin_amdgcn_mfma_f32_32x32x16_f16(av1, pbf[c], o1, 0, 0, 0);
        }
        __builtin_amdgcn_s_setprio(0);

        __syncthreads();   // writes of buf[t+1] done; reads of buf[t] done
    }

    // own-group l(q=ln) lives on h=0 lanes in o1[8]
    const float lown = __shfl(o1[8], ln);

    const int row = wg * 32 + ln;
    if (g == 1) {
        // write partial O^T (f32) + partial l
        #pragma unroll
        for (int q4 = 0; q4 < 4; q4++) {
            f32x4 tq = { o0[4 * q4], o0[4 * q4 + 1], o0[4 * q4 + 2], o0[4 * q4 + 3] };
            *(f32x4*)&sm.e.Of[row][8 * q4 + 4 * h] = tq;
        }
        #pragma unroll
        for (int q4 = 0; q4 < 2; q4++) {
            f32x4 tq = { o1[4 * q4], o1[4 * q4 + 1], o1[4 * q4 + 2], o1[4 * q4 + 3] };
            *(f32x4*)&sm.e.Of[row][32 + 8 * q4 + 4 * h] = tq;
        }
        if (h == 0) sm.e.lv[row] = o1[8];
    }
    __syncthreads();
    if (g == 0) {
        // add group-1 partials, normalize, transpose to Ot
        #pragma unroll
        for (int q4 = 0; q4 < 4; q4++) {
            const f32x4 tq = *(const f32x4*)&sm.e.Of[row][8 * q4 + 4 * h];
            o0[4 * q4] += tq[0]; o0[4 * q4 + 1] += tq[1];
            o0[4 * q4 + 2] += tq[2]; o0[4 * q4 + 3] += tq[3];
        }
        #pragma unroll
        for (int q4 = 0; q4 < 2; q4++) {
            const f32x4 tq = *(const f32x4*)&sm.e.Of[row][32 + 8 * q4 + 4 * h];
            o1[4 * q4] += tq[0]; o1[4 * q4 + 1] += tq[1];
            o1[4 * q4 + 2] += tq[2]; o1[4 * q4 + 3] += tq[3];
        }
        const float inv = 1.f / (lown + sm.e.lv[row]);
        #pragma unroll
        for (int r = 0; r < 16; r++)
            sm.e.Ot[row][(r & 3) + 8 * (r >> 2) + 4 * h] = (_Float16)(o0[r] * inv);
        #pragma unroll
        for (int r = 0; r < 8; r++)
            sm.e.Ot[row][32 + (r & 3) + 8 * (r >> 2) + 4 * h] = (_Float16)(o1[r] * inv);
    }
    __syncthreads();
    if (g == 0) {
        const int b = bh >> 3, hd = bh & 7;
        #pragma unroll
        for (int i = 0; i < 3; i++) {
            const int c2 = i * 256 + tid;
            const int rw = c2 / 6, ch = c2 % 6;
            const int q = qt * 128 + rw;
            *(f16x8*)&ab[(size_t)(b * 2048 + q) * 384 + hd * 48 + ch * 8] =
                *(const f16x8*)&sm.e.Ot[rw][ch * 8];
        }
    }
}

// ---------------------------------------------------------------------------
// Proj GEMM: A = ab[8192][384] f16, Bt = wprojt[384][384] f16, +bias -> fp32
// 64x64 tile, BK=32, stage-ahead dbuf, ONE barrier/iter (12 total).
// ---------------------------------------------------------------------------
__global__ __launch_bounds__(256) void proj_f16(const _Float16* __restrict__ A,
                                                const _Float16* __restrict__ Bt,
                                                const float* __restrict__ bias,
                                                float* __restrict__ out)
{
    __shared__ _Float16 As[2][64][40];
    __shared__ _Float16 Bs[2][64][40];   // 20480 B
    const int tid = threadIdx.x;
    const int w = tid >> 6, lane = tid & 63, cl = lane & 15, quad = lane >> 4;
    const int bm = blockIdx.x, bn = blockIdx.y;

    f32x4 acc[4];
    const f32x4 z4 = {0.f, 0.f, 0.f, 0.f};
    #pragma unroll
    for (int t = 0; t < 4; t++) acc[t] = z4;

    const int ar = tid >> 2, ac = (tid & 3) * 8;   // 64 rows x 4 chunks of 8
    const _Float16* Ag = A  + (size_t)(bm * 64 + ar) * 384 + ac;
    const _Float16* Bg = Bt + (size_t)(bn * 64 + ar) * 384 + ac;

    f16x8 pa = *(const f16x8*)Ag;
    f16x8 pb = *(const f16x8*)Bg;
    // prologue: stage k0=0 into buf0; load k0=32
    *(f16x8*)&As[0][ar][ac] = pa;
    *(f16x8*)&Bs[0][ar][ac] = pb;
    pa = *(const f16x8*)(Ag + 32);
    pb = *(const f16x8*)(Bg + 32);
    __syncthreads();

    for (int it = 0; it < 12; ++it) {
        if (it < 11) {
            *(f16x8*)&As[(it + 1) & 1][ar][ac] = pa;
            *(f16x8*)&Bs[(it + 1) & 1][ar][ac] = pb;
            if (it < 10) {
                const int off = (it + 2) * 32;
                pa = *(const f16x8*)(Ag + off);
                pb = *(const f16x8*)(Bg + off);
            }
        }
        const f16x8 af = *(const f16x8*)&As[it & 1][w * 16 + cl][quad * 8];
        #pragma unroll
        for (int t = 0; t < 4; t++) {
            const f16x8 bf = *(const f16x8*)&Bs[it & 1][t * 16 + cl][quad * 8];
            acc[t] = __builtin_amdgcn_mfma_f32_16x16x32_f16(af, bf, acc[t], 0, 0, 0);
        }
        __syncthreads();
    }

    #pragma unroll
    for (int t = 0; t < 4; t++) {
        const int col = bn * 64 + t * 16 + cl;
        const float bv = bias[col];
        #pragma unroll
        for (int r = 0; r < 4; r++) {
            const int row = bm * 64 + w * 16 + quad * 4 + r;
            out[(size_t)row * 384 + col] = acc[t][r] + bv;
        }
    }
}

// ---------------------------------------------------------------------------
extern "C" void kernel_launch(void* const* d_in, const int* in_sizes, int n_in,
                              void* d_out, int out_size, void* d_ws, size_t ws_size,
                              hipStream_t stream) {
    const float* x     = (const float*)d_in[0];  // [4,2048,384]
    const float* Wqkv  = (const float*)d_in[1];  // [384,1152]
    const float* Wproj = (const float*)d_in[2];  // [384,384]
    const float* bproj = (const float*)d_in[3];  // [384]
    float* out = (float*)d_out;

    char* ws = (char*)d_ws;
    _Float16* xh     = (_Float16*)(ws + 0);          // 8192*384*2  = 6,291,456
    _Float16* wqkvt  = (_Float16*)(ws + 6291456);    // 1152*384*2  =   884,736
    _Float16* wprojt = (_Float16*)(ws + 7176192);    // 384*384*2   =   294,912
    _Float16* qh     = (_Float16*)(ws + 7471104);    // 32*2048*48*2 = 6,291,456
    _Float16* kh     = (_Float16*)(ws + 13762560);   // 6,291,456
    _Float16* vt     = (_Float16*)(ws + 20054016);   // 6,291,456
    _Float16* ab     = (_Float16*)(ws + 26345472);   // 6,291,456
    // total 32,636,928 B

    prep<<<400, 256, 0, stream>>>((const float4*)x, Wqkv, Wproj,
                                  (f16x4*)xh, wqkvt, wprojt);
    qkv_f16<<<dim3(64, 9), 256, 0, stream>>>(xh, wqkvt, qh, kh, vt);
    attn_f16<<<dim3(32, 16), 512, 0, stream>>>(qh, kh, vt, ab);
    proj_f16<<<dim3(128, 6), 256, 0, stream>>>(ab, wprojt, bproj, out);
}